// Round 5
// baseline (48.858 us; speedup 1.0000x reference)
//
#include <hip/hip_runtime.h>

#define N_PTS 128
#define FAR_DELTA 1e10f
#define EPS 1e-10f
#define RAYS_PER_BLOCK 8   // 256 threads / 32 lanes-per-ray

// ---------------------------------------------------------------------------
// Kernel 1: global max of depth_values. Rows are sorted ascending (per
// setup_inputs), so the global max is the max over the last column.
// atomicMax on float bits is order-preserving for positive floats; d_ws is
// zeroed before this kernel each call.
// ---------------------------------------------------------------------------
__global__ __launch_bounds__(256) void vr_depth_max(
    const float* __restrict__ depth, float* __restrict__ gmax, int n_rays)
{
    int i = blockIdx.x * blockDim.x + threadIdx.x;
    float v = 0.0f;
    if (i < n_rays) v = depth[(size_t)i * N_PTS + (N_PTS - 1)];
    #pragma unroll
    for (int off = 32; off > 0; off >>= 1)
        v = fmaxf(v, __shfl_xor(v, off, 64));
    if ((threadIdx.x & 63) == 0)
        atomicMax((int*)gmax, __float_as_int(v));
}

// ---------------------------------------------------------------------------
// Kernel 2: fused volume rendering. 32 lanes per ray, lane sl owns points
// 4sl..4sl+3. depth/density loads are dense dwordx4 per segment. feature
// (60% of bytes) is staged through LDS: the block's 8 rays = 12 KB are
// loaded with 3 block-wide, perfectly-coalesced dwordx4 passes (16 B/lane
// dense), then consumed as 48 B/lane ds_read_b128x3. The scan/weight
// computation depends only on depth/density, so it overlaps the staging
// loads; one __syncthreads before the LDS reads.
//
// s at the global last point (sl==31, elem 3) is ~rho*1e10 and must NOT
// enter the scan totals ("inclusive - own" would cancel catastrophically);
// the reference's exclusive shift drops that element entirely, so we zero
// it in the total. No exclusive prefix ever contains it.
// ---------------------------------------------------------------------------
__global__ __launch_bounds__(256) void vr_main(
    const float* __restrict__ depth,    // [n_rays, 128]
    const float* __restrict__ density,  // [n_rays, 128, 1]
    const float* __restrict__ feature,  // [n_rays, 128, 3]
    const float* __restrict__ gmax_ptr, // [1]
    float* __restrict__ feat_out,       // [n_rays, 3]
    float* __restrict__ depth_out,      // [n_rays, 1]
    int n_rays)
{
    __shared__ float4 sf[RAYS_PER_BLOCK * 96];   // 8 rays x 384 floats = 12 KB

    const int t   = threadIdx.x;
    const int q   = t >> 5;           // ray segment within block
    const int sl  = t & 31;           // lane within ray
    const int ray = blockIdx.x * RAYS_PER_BLOCK + q;

    // ---- stage feature: 3 block-wide dense dwordx4 passes ----
    {
        const float4* fg = (const float4*)(feature + (size_t)blockIdx.x * RAYS_PER_BLOCK * N_PTS * 3);
        #pragma unroll
        for (int k = 0; k < 3; ++k)
            sf[k * 256 + t] = fg[k * 256 + t];
    }

    // ---- own depth/density loads (dense dwordx4 per segment) ----
    const float4* dp4 = (const float4*)(depth   + (size_t)ray * N_PTS);
    const float4* rp4 = (const float4*)(density + (size_t)ray * N_PTS);
    float4 d4 = dp4[sl];
    float4 r4 = rp4[sl];

    const float inv_gmax = 1.0f / gmax_ptr[0];

    // ---- deltas ----
    float nd = __shfl_down(d4.x, 1, 32);   // next lane's first depth
    float delta0 = d4.y - d4.x;
    float delta1 = d4.z - d4.y;
    float delta2 = d4.w - d4.z;
    float delta3 = (sl == 31) ? FAR_DELTA : (nd - d4.w);

    // ---- s = rho*(delta+eps), local prefix, segmented scan of totals ----
    float s0 = r4.x * (delta0 + EPS);
    float s1 = r4.y * (delta1 + EPS);
    float s2 = r4.z * (delta2 + EPS);
    float s3 = r4.w * (delta3 + EPS);

    float p1 = s0;
    float p2 = s0 + s1;
    float p3 = p2 + s2;
    float tt = p3 + ((sl == 31) ? 0.0f : s3);  // drop the huge last element

    float inc = tt;
    #pragma unroll
    for (int off = 1; off < 32; off <<= 1) {
        float n = __shfl_up(inc, off, 32);
        if (sl >= off) inc += n;
    }
    float excl = inc - tt;  // sum of totals of lanes 0..sl-1 (all benign)

    // ---- weights: trans * (1 - exp(-rho*delta + eps)) ----
    float w0 = __expf(-excl)        * (1.0f - __expf(fmaf(-r4.x, delta0, EPS)));
    float w1 = __expf(-(excl + p1)) * (1.0f - __expf(fmaf(-r4.y, delta1, EPS)));
    float w2 = __expf(-(excl + p2)) * (1.0f - __expf(fmaf(-r4.z, delta2, EPS)));
    float w3 = __expf(-(excl + p3)) * (1.0f - __expf(fmaf(-r4.w, delta3, EPS)));

    float accd = (w0 * d4.x + w1 * d4.y + w2 * d4.z + w3 * d4.w) * inv_gmax;

    // ---- consume staged feature ----
    __syncthreads();
    float4 f0 = sf[q * 96 + sl * 3 + 0];   // {p0.r p0.g p0.b p1.r}
    float4 f1 = sf[q * 96 + sl * 3 + 1];   // {p1.g p1.b p2.r p2.g}
    float4 f2 = sf[q * 96 + sl * 3 + 2];   // {p2.b p3.r p3.g p3.b}

    float acc0 = w0 * f0.x + w1 * f0.w + w2 * f1.z + w3 * f2.y;
    float acc1 = w0 * f0.y + w1 * f1.x + w2 * f1.w + w3 * f2.z;
    float acc2 = w0 * f0.z + w1 * f1.y + w2 * f2.x + w3 * f2.w;

    // ---- 32-lane segmented sum reduce ----
    #pragma unroll
    for (int off = 16; off > 0; off >>= 1) {
        acc0 += __shfl_xor(acc0, off, 32);
        acc1 += __shfl_xor(acc1, off, 32);
        acc2 += __shfl_xor(acc2, off, 32);
        accd += __shfl_xor(accd, off, 32);
    }

    if (sl == 0 && ray < n_rays) {
        float* fo = feat_out + (size_t)ray * 3;
        fo[0] = acc0;
        fo[1] = acc1;
        fo[2] = acc2;
        depth_out[ray] = accd;
    }
}

extern "C" void kernel_launch(void* const* d_in, const int* in_sizes, int n_in,
                              void* d_out, int out_size, void* d_ws, size_t ws_size,
                              hipStream_t stream)
{
    const float* depth   = (const float*)d_in[0];
    const float* density = (const float*)d_in[1];
    const float* feature = (const float*)d_in[2];

    const int n_rays = in_sizes[0] / N_PTS;

    float* out       = (float*)d_out;
    float* feat_out  = out;                        // [n_rays, 3]
    float* depth_out = out + (size_t)n_rays * 3;   // [n_rays, 1]
    float* gmax      = (float*)d_ws;

    (void)hipMemsetAsync(d_ws, 0, sizeof(float), stream);

    {
        int threads = 256;
        int blocks  = (n_rays + threads - 1) / threads;
        vr_depth_max<<<blocks, threads, 0, stream>>>(depth, gmax, n_rays);
    }
    {
        // 32 lanes per ray, 8 rays per 256-thread block
        int threads = 256;
        int blocks  = n_rays / RAYS_PER_BLOCK;
        vr_main<<<blocks, threads, 0, stream>>>(depth, density, feature, gmax,
                                                feat_out, depth_out, n_rays);
    }
}

// Round 6
// 37.295 us; speedup vs baseline: 1.3101x; 1.3101x over previous
//
#include <hip/hip_runtime.h>

#define N_PTS 128
#define FAR_DELTA 1e10f
#define EPS 1e-10f
#define RPB 8   // rays per 256-thread block (32 lanes per ray)

// ---------------------------------------------------------------------------
// Kernel 1: fused volume rendering. 32 lanes per ray, lane sl owns points
// 4sl..4sl+3; all global loads are dwordx4 (direct, no LDS staging — measured
// neutral/negative in round 5). depth_out is written UNNORMALIZED; the
// global depth max is derived for free from registers: rows are sorted, so
// ray max = d4.w at sl==31. Per-block max (8 rays) goes to blk_max[block]
// via a tiny LDS reduce — plain stores, no atomics, no memset needed.
//
// s at the global last point (sl==31, elem 3) is ~rho*1e10 and must NOT
// enter the scan totals ("inclusive - own" would cancel catastrophically);
// the reference's exclusive shift drops that element entirely, so we zero
// it in the total. No exclusive prefix ever contains it.
// ---------------------------------------------------------------------------
__global__ __launch_bounds__(256) void vr_main(
    const float* __restrict__ depth,    // [n_rays, 128]
    const float* __restrict__ density,  // [n_rays, 128, 1]
    const float* __restrict__ feature,  // [n_rays, 128, 3]
    float* __restrict__ feat_out,       // [n_rays, 3]
    float* __restrict__ depth_out,      // [n_rays, 1] (unnormalized here)
    float* __restrict__ blk_max,        // [gridDim.x]
    int n_rays)
{
    __shared__ float bmax[RPB];

    const int t   = threadIdx.x;
    const int q   = t >> 5;           // ray segment within block
    const int sl  = t & 31;           // lane within ray
    const int ray = blockIdx.x * RPB + q;

    // ---- vectorized loads: lane sl owns points 4sl..4sl+3 ----
    const float4* dp4 = (const float4*)(depth   + (size_t)ray * N_PTS);
    const float4* rp4 = (const float4*)(density + (size_t)ray * N_PTS);
    const float4* fp4 = (const float4*)(feature + (size_t)ray * N_PTS * 3);

    float4 d4 = dp4[sl];
    float4 r4 = rp4[sl];
    float4 f0 = fp4[sl * 3 + 0];   // {p0.r p0.g p0.b p1.r}
    float4 f1 = fp4[sl * 3 + 1];   // {p1.g p1.b p2.r p2.g}
    float4 f2 = fp4[sl * 3 + 2];   // {p2.b p3.r p3.g p3.b}

    // ray max depth = last sample (rows sorted ascending)
    if (sl == 31) bmax[q] = d4.w;

    // ---- deltas ----
    float nd = __shfl_down(d4.x, 1, 32);   // next lane's first depth
    float delta0 = d4.y - d4.x;
    float delta1 = d4.z - d4.y;
    float delta2 = d4.w - d4.z;
    float delta3 = (sl == 31) ? FAR_DELTA : (nd - d4.w);

    // ---- s = rho*(delta+eps), local prefix, segmented scan of totals ----
    float s0 = r4.x * (delta0 + EPS);
    float s1 = r4.y * (delta1 + EPS);
    float s2 = r4.z * (delta2 + EPS);
    float s3 = r4.w * (delta3 + EPS);

    float p1 = s0;
    float p2 = s0 + s1;
    float p3 = p2 + s2;
    float tt = p3 + ((sl == 31) ? 0.0f : s3);  // drop the huge last element

    float inc = tt;
    #pragma unroll
    for (int off = 1; off < 32; off <<= 1) {
        float n = __shfl_up(inc, off, 32);
        if (sl >= off) inc += n;
    }
    float excl = inc - tt;  // sum of totals of lanes 0..sl-1 (all benign)

    // ---- weights: trans * (1 - exp(-rho*delta + eps)) ----
    float w0 = __expf(-excl)        * (1.0f - __expf(fmaf(-r4.x, delta0, EPS)));
    float w1 = __expf(-(excl + p1)) * (1.0f - __expf(fmaf(-r4.y, delta1, EPS)));
    float w2 = __expf(-(excl + p2)) * (1.0f - __expf(fmaf(-r4.z, delta2, EPS)));
    float w3 = __expf(-(excl + p3)) * (1.0f - __expf(fmaf(-r4.w, delta3, EPS)));

    // ---- accumulate rgb + (unnormalized) depth ----
    float acc0 = w0 * f0.x + w1 * f0.w + w2 * f1.z + w3 * f2.y;
    float acc1 = w0 * f0.y + w1 * f1.x + w2 * f1.w + w3 * f2.z;
    float acc2 = w0 * f0.z + w1 * f1.y + w2 * f2.x + w3 * f2.w;
    float accd = w0 * d4.x + w1 * d4.y + w2 * d4.z + w3 * d4.w;

    // ---- 32-lane segmented sum reduce ----
    #pragma unroll
    for (int off = 16; off > 0; off >>= 1) {
        acc0 += __shfl_xor(acc0, off, 32);
        acc1 += __shfl_xor(acc1, off, 32);
        acc2 += __shfl_xor(acc2, off, 32);
        accd += __shfl_xor(accd, off, 32);
    }

    if (sl == 0 && ray < n_rays) {
        float* fo = feat_out + (size_t)ray * 3;
        fo[0] = acc0;
        fo[1] = acc1;
        fo[2] = acc2;
        depth_out[ray] = accd;
    }

    // ---- per-block depth max -> blk_max (plain store, no init needed) ----
    __syncthreads();
    if (t == 0) {
        float m = bmax[0];
        #pragma unroll
        for (int i = 1; i < RPB; ++i) m = fmaxf(m, bmax[i]);
        blk_max[blockIdx.x] = m;
    }
}

// ---------------------------------------------------------------------------
// Kernel 2: reduce the per-block maxes (L2-hot) and scale depth_out in
// place by 1/gmax. Every block computes the same gmax redundantly (8192
// loads/block, trivial), then scales its 256-ray slice.
// ---------------------------------------------------------------------------
__global__ __launch_bounds__(256) void vr_epilogue(
    const float* __restrict__ blk_max, float* __restrict__ depth_out,
    int nb, int n_rays)
{
    const int t = threadIdx.x;

    float m = 0.0f;
    for (int i = t; i < nb; i += 256) m = fmaxf(m, blk_max[i]);
    #pragma unroll
    for (int off = 32; off > 0; off >>= 1)
        m = fmaxf(m, __shfl_xor(m, off, 64));

    __shared__ float wm[4];
    if ((t & 63) == 0) wm[t >> 6] = m;
    __syncthreads();
    float gm = fmaxf(fmaxf(wm[0], wm[1]), fmaxf(wm[2], wm[3]));

    int i = blockIdx.x * 256 + t;
    if (i < n_rays) depth_out[i] *= (1.0f / gm);
}

extern "C" void kernel_launch(void* const* d_in, const int* in_sizes, int n_in,
                              void* d_out, int out_size, void* d_ws, size_t ws_size,
                              hipStream_t stream)
{
    const float* depth   = (const float*)d_in[0];
    const float* density = (const float*)d_in[1];
    const float* feature = (const float*)d_in[2];

    const int n_rays = in_sizes[0] / N_PTS;

    float* out       = (float*)d_out;
    float* feat_out  = out;                        // [n_rays, 3]
    float* depth_out = out + (size_t)n_rays * 3;   // [n_rays, 1]
    float* blk_max   = (float*)d_ws;               // [n_rays/RPB] floats

    const int nb = n_rays / RPB;                   // 8192 blocks

    vr_main<<<nb, 256, 0, stream>>>(depth, density, feature,
                                    feat_out, depth_out, blk_max, n_rays);

    const int eb = (n_rays + 255) / 256;           // 256 blocks
    vr_epilogue<<<eb, 256, 0, stream>>>(blk_max, depth_out, nb, n_rays);
}